// Round 7
// baseline (314.401 us; speedup 1.0000x reference)
//
#include <hip/hip_runtime.h>
#include <hip/hip_bf16.h>

// Problem constants
#define S_      1024
#define B_      2
#define H_      1024
#define E_      8
#define FFN_    1408
#define TWO_FFN 2816
#define T_      2048          // B_*S_
#define MAXSLOTS 5120
#define NB_CONV 512             // convert+gate blocks
#define TSZ     (128 * 64)      // one LDS tile buffer (ushort elems)

typedef float  f32x4 __attribute__((ext_vector_type(4)));
typedef short  s16x8 __attribute__((ext_vector_type(8)));

// ---------- helpers ----------
__device__ __forceinline__ unsigned short f2bf(float f) {
    unsigned u = __float_as_uint(f);
    u += 0x7fffu + ((u >> 16) & 1u);          // round-to-nearest-even
    return (unsigned short)(u >> 16);
}
// packed f32 pair -> bf16 pair (compiler emits v_cvt_pk_bf16_f32, RTNE)
__device__ __forceinline__ unsigned pk2(float a, float b) {
    __hip_bfloat162 h = __float22bfloat162_rn(make_float2(a, b));
    unsigned u; __builtin_memcpy(&u, &h, 4); return u;
}
__device__ __forceinline__ void async16(const void* g, void* l) {
    __builtin_amdgcn_global_load_lds(
        (const __attribute__((address_space(1))) unsigned int*)(unsigned long long)g,
        (__attribute__((address_space(3))) unsigned int*)(unsigned long long)l,
        16, 0, 0);
}
__device__ __forceinline__ size_t xrow_off(int t) {
    return (size_t)(t & (S_ - 1)) * (B_ * H_) + (size_t)(t >> 10) * H_;
}

// ---------- B staging building blocks ----------
// Load 8 coalesced float4 rows (k..k+7 of 4 n-columns) of the fp32 [k][n] panel.
__device__ __forceinline__ void load8(f32x4 v[8], const float* __restrict__ p, size_t C) {
#pragma unroll
    for (int j = 0; j < 8; j++) v[j] = *(const f32x4*)(p + (size_t)j * C);
}
// Convert + write: one b128 per n-row (8 consecutive k packed).
__device__ __forceinline__ void stage_wr(const f32x4 v[8], unsigned* __restrict__ base,
                                         const int off[4]) {
#pragma unroll
    for (int i = 0; i < 4; i++) {
        uint4 q;
        q.x = pk2(v[0][i], v[1][i]);
        q.y = pk2(v[2][i], v[3][i]);
        q.z = pk2(v[4][i], v[5][i]);
        q.w = pk2(v[6][i], v[7][i]);
        *(uint4*)(base + off[i]) = q;
    }
}
// One 64-k MFMA step over the current LDS buffers.
__device__ __forceinline__ void mfma_step(const unsigned short* __restrict__ As,
                                          const unsigned short* __restrict__ Bs,
                                          f32x4 acc[4][4], int rowB, int colB, int lane) {
    int sw = (lane & 7) << 3;
#pragma unroll
    for (int kk = 0; kk < 64; kk += 32) {
        int kr = (kk + ((lane >> 4) << 3)) ^ sw;
        s16x8 af[4], bf[4];
#pragma unroll
        for (int mi = 0; mi < 4; mi++) af[mi] = *(const s16x8*)&As[(rowB + mi * 16 + (lane & 15)) * 64 + kr];
#pragma unroll
        for (int ni = 0; ni < 4; ni++) bf[ni] = *(const s16x8*)&Bs[(colB + ni * 16 + (lane & 15)) * 64 + kr];
#pragma unroll
        for (int mi = 0; mi < 4; mi++)
#pragma unroll
            for (int ni = 0; ni < 4; ni++)
                acc[mi][ni] = __builtin_amdgcn_mfma_f32_16x16x32_bf16(af[mi], bf[ni], acc[mi][ni], 0, 0, 0);
    }
}

// ---------- 1. prep: convert activations to bf16 + gate top-2 ----------
__global__ void k_prep(const float* __restrict__ hs, const float* __restrict__ gw,
                       unsigned short* __restrict__ xb,
                       int* __restrict__ topkI, float* __restrict__ topkW) {
    int cb = blockIdx.x, tid = threadIdx.x;
    int wid = tid >> 6, lane = tid & 63;
    int t = cb * 4 + wid;
    const float* xr = hs + xrow_off(t);
    unsigned short* xo = xb + (size_t)t * H_;
    float acc[E_];
#pragma unroll
    for (int e = 0; e < E_; e++) acc[e] = 0.f;
#pragma unroll
    for (int p = 0; p < 4; p++) {
        int h = p * 256 + lane * 4;
        const float4 v = *(const float4*)(xr + h);
        unsigned short o[4] = { f2bf(v.x), f2bf(v.y), f2bf(v.z), f2bf(v.w) };
        *(uint2*)(xo + h) = *(const uint2*)o;
#pragma unroll
        for (int e = 0; e < E_; e++) {
            const float4 g = *(const float4*)(gw + e * H_ + h);
            acc[e] += v.x * g.x + v.y * g.y + v.z * g.z + v.w * g.w;
        }
    }
#pragma unroll
    for (int e = 0; e < E_; e++)
        for (int off = 32; off > 0; off >>= 1) acc[e] += __shfl_down(acc[e], off);
    if (lane == 0) {
        float l0 = -1e30f, l1 = -1e30f; int i0 = 0, i1 = 0;
#pragma unroll
        for (int e = 0; e < E_; e++) {
            float v = acc[e];
            if (v > l0)      { l1 = l0; i1 = i0; l0 = v; i0 = e; }
            else if (v > l1) { l1 = v;  i1 = e; }
        }
        float p1 = expf(l1 - l0);                 // p0 = 1
        float w0 = 1.f / (1.f + p1);
        float w1s = 1.f - w0;
        topkI[2 * t] = i0; topkI[2 * t + 1] = i1;
        topkW[2 * t] = w0; topkW[2 * t + 1] = w1s;
    }
}

// ---------- 2. fused histogram + route + assign (one block) ----------
// ctrl ints: [40+e]=ntile(e)  [48+e]=slotBase(e)
__global__ void k_routeassign(const int* __restrict__ topkI, const float* __restrict__ topkW,
                              int* __restrict__ ctrl, int* __restrict__ perm,
                              int* __restrict__ slotOfTok) {
    __shared__ int s_wcnt[4][E_];
    __shared__ int s_base[E_];
    __shared__ int s_cur[E_];
    int tid = threadIdx.x, wid = tid >> 6, lane = tid & 63;
    int cnt[E_];
#pragma unroll
    for (int j = 0; j < E_; j++) cnt[j] = 0;
    for (int i = tid; i < 2 * T_; i += 256) {
        int e = topkI[i];
#pragma unroll
        for (int j = 0; j < E_; j++) cnt[j] += (e == j);
    }
#pragma unroll
    for (int j = 0; j < E_; j++)
        for (int off = 32; off > 0; off >>= 1) cnt[j] += __shfl_down(cnt[j], off);
    if (lane == 0) {
#pragma unroll
        for (int j = 0; j < E_; j++) s_wcnt[wid][j] = cnt[j];
    }
    __syncthreads();
    if (tid == 0) {
        int b = 0;
        for (int e = 0; e < E_; e++) {
            int n = s_wcnt[0][e] + s_wcnt[1][e] + s_wcnt[2][e] + s_wcnt[3][e];
            int ntile = (n + 127) >> 7;
            s_base[e] = b;
            ctrl[40 + e] = ntile;
            ctrl[48 + e] = b;
            b += ntile * 128;
        }
#pragma unroll
        for (int e = 0; e < E_; e++) s_cur[e] = 0;
    }
    __syncthreads();
    for (int s = tid; s < MAXSLOTS; s += 256) perm[s] = 0;   // padded slots -> token 0 (safe)
    __syncthreads();
    for (int t = tid; t < T_; t += 256) {
#pragma unroll
        for (int k = 0; k < 2; k++) {
            int e = topkI[2 * t + k];
            int pos = atomicAdd(&s_cur[e], 1);   // LDS atomic
            int slot = s_base[e] + pos;
            perm[slot] = t;
            slotOfTok[2 * t + k] = slot;
        }
    }
}

// ---------- 3. GEMM1 + fused swiglu epilogue ----------
// Single-buffered As/Bs (32 KB total) -> 4 blocks/CU target. m97-style
// 2-barrier K-step; bv holds B(s+1) fp32 in regs across the MFMA phase so its
// vmcnt wait is covered; occupancy (not pipeline depth) hides the barrier drain.
__global__ __launch_bounds__(256, 4) void k_gemm1(
    const unsigned short* __restrict__ xb, const float* __restrict__ w1,
    const int* __restrict__ ctrl, const int* __restrict__ perm,
    unsigned short* __restrict__ A2) {
    int b  = blockIdx.x;
    int p  = ((b >> 7) << 3) | (b & 7);         // 0..175
    int ti = (b >> 3) & 15;
    int e  = p / 22;
    int ct = p - e * 22;                        // 0..21
    if (ti >= ctrl[40 + e]) return;
    int slot0 = ctrl[48 + e] + ti * 128;
    __shared__ __align__(16) unsigned short smem[2 * TSZ];   // As | Bs = 32 KB, reused as fp32 upLds
    unsigned short* As = smem;
    unsigned short* Bs = smem + TSZ;
    int tid = threadIdx.x, wid = tid >> 6, lane = tid & 63;

    // A staging map (bf16 activations, async global->LDS, pre-swizzled source)
    const unsigned short* aPtr[4];
    int lAoff[4];
#pragma unroll
    for (int i = 0; i < 4; i++) {
        int c = (wid * 4 + i) * 64 + lane;      // chunk id 0..1023
        int r = c >> 3;
        int qd = (c & 7) ^ (r & 7);             // XOR swizzle
        int tok = perm[slot0 + r];
        aPtr[i] = xb + (size_t)tok * H_ + qd * 8;
        lAoff[i] = c * 8;
    }
    // B staging map
    int h1 = tid >> 7, kp = (tid >> 4) & 7, nq = tid & 15;
    int rb = h1 * 64 + nq * 4;
    const float* bsrc = w1 + (size_t)e * (H_ * TWO_FFN)
                        + (h1 ? (FFN_ + ct * 64) : (ct * 64)) + nq * 4
                        + (size_t)(kp * 8) * TWO_FFN;
    int bwOff[4];
#pragma unroll
    for (int i = 0; i < 4; i++)
        bwOff[i] = (rb + i) * 32 + ((kp ^ ((rb + i) & 7)) << 2);

    f32x4 acc[4][4];
#pragma unroll
    for (int mi = 0; mi < 4; mi++)
#pragma unroll
        for (int ni = 0; ni < 4; ni++) acc[mi][ni] = (f32x4){0.f, 0.f, 0.f, 0.f};
    int wm = wid & 1, wn = wid >> 1;
    int rowB = wm * 64, colB = wn * 64;

    f32x4 bv[8];
    // ---- prologue ----
    load8(bv, bsrc, TWO_FFN);                                   // B(0)
    stage_wr(bv, (unsigned*)Bs, bwOff);                         // waits B(0)
#pragma unroll
    for (int i = 0; i < 4; i++) async16(aPtr[i], As + lAoff[i]); // A(0)
    load8(bv, bsrc + (size_t)64 * TWO_FFN, TWO_FFN);            // B(1) in flight
    __syncthreads();

#pragma unroll 1
    for (int s = 0; s < 16; s++) {
        mfma_step(As, Bs, acc, rowB, colB, lane);
        if (s == 15) break;
        __syncthreads();                                        // all waves done reading As/Bs
        stage_wr(bv, (unsigned*)Bs, bwOff);                     // B(s+1): bv in flight since s-1
        size_t ka = (size_t)(s + 1) * 64;
#pragma unroll
        for (int i = 0; i < 4; i++) async16(aPtr[i] + ka, As + lAoff[i]);   // A(s+1)
        if (s < 14) load8(bv, bsrc + (size_t)(s + 2) * 64 * TWO_FFN, TWO_FFN); // B(s+2)
        __syncthreads();                                        // As/Bs ready for next step
    }
    __syncthreads();
    // ---- fused swiglu epilogue ----
    float* upLds = (float*)smem;                // 128 x 64 fp32 = 32 KB
    if (wn == 1) {
#pragma unroll
        for (int mi = 0; mi < 4; mi++)
#pragma unroll
            for (int ni = 0; ni < 4; ni++)
#pragma unroll
                for (int r = 0; r < 4; r++) {
                    int m = rowB + mi * 16 + (lane >> 4) * 4 + r;
                    int u = ni * 16 + (lane & 15);
                    upLds[m * 64 + u] = acc[mi][ni][r];
                }
    }
    __syncthreads();
    if (wn == 0) {
#pragma unroll
        for (int mi = 0; mi < 4; mi++)
#pragma unroll
            for (int r = 0; r < 4; r++) {
                int m = rowB + mi * 16 + (lane >> 4) * 4 + r;
                unsigned short* arow = A2 + (size_t)(slot0 + m) * FFN_ + ct * 64;
#pragma unroll
                for (int ni = 0; ni < 4; ni++) {
                    int gl = ni * 16 + (lane & 15);
                    float g = acc[mi][ni][r];
                    float u = upLds[m * 64 + gl];
                    float s = g / (1.f + expf(-g));
                    arow[gl] = f2bf(s * u);
                }
            }
    }
}

// ---------- 4. GEMM2 (split-K=2): A2[128,1408] @ w2^T -> Yp bf16 partials ----------
__global__ __launch_bounds__(256, 4) void k_gemm2(
    const unsigned short* __restrict__ A2, const float* __restrict__ w2,
    const int* __restrict__ ctrl, unsigned short* __restrict__ Yp) {
    int b  = blockIdx.x;
    int p  = ((b >> 7) << 3) | (b & 7);         // 0..127
    int ti = (b >> 3) & 15;
    int e  = p >> 4;
    int ct = (p >> 1) & 7;                      // 0..7
    int ks = p & 1;
    if (ti >= ctrl[40 + e]) return;
    int slot0 = ctrl[48 + e] + ti * 128;
    __shared__ __align__(16) unsigned short As[TSZ];
    __shared__ __align__(16) unsigned short Bs[TSZ];
    int tid = threadIdx.x, wid = tid >> 6, lane = tid & 63;

    const unsigned short* aPtr[4];
    int lAoff[4];
#pragma unroll
    for (int i = 0; i < 4; i++) {
        int c = (wid * 4 + i) * 64 + lane;
        int r = c >> 3;
        int qd = (c & 7) ^ (r & 7);
        aPtr[i] = A2 + (size_t)(slot0 + r) * FFN_ + qd * 8;
        lAoff[i] = c * 8;
    }
    int h1 = tid >> 7, kp = (tid >> 4) & 7, nq = tid & 15;
    int rb = h1 * 64 + nq * 4;
    int kbeg = ks * (FFN_ / 2);                 // 11 steps each
    const float* bsrc = w2 + (size_t)e * (FFN_ * H_)
                        + ct * 128 + h1 * 64 + nq * 4
                        + (size_t)(kp * 8 + kbeg) * H_;
    int bwOff[4];
#pragma unroll
    for (int i = 0; i < 4; i++)
        bwOff[i] = (rb + i) * 32 + ((kp ^ ((rb + i) & 7)) << 2);

    f32x4 acc[4][4];
#pragma unroll
    for (int mi = 0; mi < 4; mi++)
#pragma unroll
        for (int ni = 0; ni < 4; ni++) acc[mi][ni] = (f32x4){0.f, 0.f, 0.f, 0.f};
    int wm = wid & 1, wn = wid >> 1;
    int rowB = wm * 64, colB = wn * 64;

    f32x4 bv[8];
    // ---- prologue ----
    load8(bv, bsrc, H_);                                        // B(0)
    stage_wr(bv, (unsigned*)Bs, bwOff);
#pragma unroll
    for (int i = 0; i < 4; i++) async16(aPtr[i] + kbeg, As + lAoff[i]);       // A(0)
    load8(bv, bsrc + (size_t)64 * H_, H_);                      // B(1)
    __syncthreads();

#pragma unroll 1
    for (int s = 0; s < 11; s++) {
        mfma_step(As, Bs, acc, rowB, colB, lane);
        if (s == 10) break;
        __syncthreads();
        stage_wr(bv, (unsigned*)Bs, bwOff);                     // B(s+1)
        size_t ka = (size_t)(s + 1) * 64;
#pragma unroll
        for (int i = 0; i < 4; i++) async16(aPtr[i] + kbeg + ka, As + lAoff[i]);  // A(s+1)
        if (s < 9) load8(bv, bsrc + (size_t)(s + 2) * 64 * H_, H_);               // B(s+2)
        __syncthreads();
    }
    unsigned short* yp = Yp + (size_t)ks * MAXSLOTS * H_;
#pragma unroll
    for (int mi = 0; mi < 4; mi++)
#pragma unroll
        for (int r = 0; r < 4; r++) {
            int m = rowB + mi * 16 + (lane >> 4) * 4 + r;
#pragma unroll
            for (int ni = 0; ni < 4; ni++) {
                int n = colB + ni * 16 + (lane & 15);
                yp[(size_t)(slot0 + m) * H_ + ct * 128 + n] = f2bf(acc[mi][ni][r]);
            }
        }
}

// ---------- 5. combine (bf16 partials) ----------
__global__ void k_combine(const unsigned short* __restrict__ Yp, const int* __restrict__ slotOfTok,
                          const float* __restrict__ topkW, float* __restrict__ out) {
    int t = blockIdx.x;
    int h = threadIdx.x * 4;
    int sA = slotOfTok[2 * t], sB = slotOfTok[2 * t + 1];
    float wA = topkW[2 * t],   wB = topkW[2 * t + 1];
    const unsigned short* pA0 = Yp + (size_t)sA * H_ + h;
    const unsigned short* pA1 = Yp + ((size_t)MAXSLOTS + sA) * H_ + h;
    const unsigned short* pB0 = Yp + (size_t)sB * H_ + h;
    const unsigned short* pB1 = Yp + ((size_t)MAXSLOTS + sB) * H_ + h;
    unsigned short a0[4], a1[4], b0[4], b1[4];
    *(uint2*)a0 = *(const uint2*)pA0;
    *(uint2*)a1 = *(const uint2*)pA1;
    *(uint2*)b0 = *(const uint2*)pB0;
    *(uint2*)b1 = *(const uint2*)pB1;
    float4 r;
    float* rp = (float*)&r;
#pragma unroll
    for (int i = 0; i < 4; i++) {
        float av = __uint_as_float(((unsigned)a0[i]) << 16) + __uint_as_float(((unsigned)a1[i]) << 16);
        float bv = __uint_as_float(((unsigned)b0[i]) << 16) + __uint_as_float(((unsigned)b1[i]) << 16);
        rp[i] = wA * av + wB * bv;
    }
    *(float4*)(out + xrow_off(t) + h) = r;
}

extern "C" void kernel_launch(void* const* d_in, const int* in_sizes, int n_in,
                              void* d_out, int out_size, void* d_ws, size_t ws_size,
                              hipStream_t stream) {
    (void)in_sizes; (void)n_in; (void)ws_size; (void)out_size;
    const float* hs = (const float*)d_in[0];
    const float* gw = (const float*)d_in[1];
    const float* w1 = (const float*)d_in[2];
    const float* w2 = (const float*)d_in[3];
    float* out = (float*)d_out;
    char* ws = (char*)d_ws;

    int*            ctrl   = (int*)ws;                                  // 1 KB
    int*            topkI  = (int*)(ws + (16u << 10));                  // 16 KB
    float*          topkW  = (float*)(ws + (48u << 10));                // 16 KB
    int*            perm   = (int*)(ws + (80u << 10));                  // 20 KB
    int*            slotOfTok = (int*)(ws + (144u << 10));              // 16 KB
    unsigned short* xb    = (unsigned short*)(ws + (1ull  << 20));      // 4 MiB
    unsigned short* A2    = (unsigned short*)(ws + (8ull  << 20));      // 13.75 MiB
    unsigned short* Yp    = (unsigned short*)(ws + (24ull << 20));      // 20 MiB -> end ~44 MiB

    k_prep<<<NB_CONV, 256, 0, stream>>>(hs, gw, xb, topkI, topkW);
    k_routeassign<<<1, 256, 0, stream>>>(topkI, topkW, ctrl, perm, slotOfTok);
    k_gemm1<<<dim3(22 * 128), 256, 0, stream>>>(xb, w1, ctrl, perm, A2);
    k_gemm2<<<dim3(16 * 128), 256, 0, stream>>>(A2, w2, ctrl, Yp);
    k_combine<<<2048, 256, 0, stream>>>(Yp, slotOfTok, topkW, out);
}

// Round 8
// 268.186 us; speedup vs baseline: 1.1723x; 1.1723x over previous
//
#include <hip/hip_runtime.h>
#include <hip/hip_bf16.h>

// Problem constants
#define S_      1024
#define B_      2
#define H_      1024
#define E_      8
#define FFN_    1408
#define TWO_FFN 2816
#define T_      2048          // B_*S_
#define MAXSLOTS 5120
#define NB_CONV 512             // convert+gate blocks
#define TSZ     (128 * 64)      // one LDS tile buffer (ushort elems)

typedef float  f32x4 __attribute__((ext_vector_type(4)));
typedef short  s16x8 __attribute__((ext_vector_type(8)));

// ---------- helpers ----------
__device__ __forceinline__ unsigned short f2bf(float f) {
    unsigned u = __float_as_uint(f);
    u += 0x7fffu + ((u >> 16) & 1u);          // round-to-nearest-even
    return (unsigned short)(u >> 16);
}
// packed f32 pair -> bf16 pair (compiler emits v_cvt_pk_bf16_f32, RTNE)
__device__ __forceinline__ unsigned pk2(float a, float b) {
    __hip_bfloat162 h = __float22bfloat162_rn(make_float2(a, b));
    unsigned u; __builtin_memcpy(&u, &h, 4); return u;
}
__device__ __forceinline__ void async16(const void* g, void* l) {
    __builtin_amdgcn_global_load_lds(
        (const __attribute__((address_space(1))) unsigned int*)(unsigned long long)g,
        (__attribute__((address_space(3))) unsigned int*)(unsigned long long)l,
        16, 0, 0);
}
__device__ __forceinline__ size_t xrow_off(int t) {
    return (size_t)(t & (S_ - 1)) * (B_ * H_) + (size_t)(t >> 10) * H_;
}

// ---------- B staging building blocks ----------
// Load 8 coalesced float4 rows (k..k+7 of 4 n-columns) of the fp32 [k][n] panel.
__device__ __forceinline__ void load8(f32x4 v[8], const float* __restrict__ p, size_t C) {
#pragma unroll
    for (int j = 0; j < 8; j++) v[j] = *(const f32x4*)(p + (size_t)j * C);
}
// Convert + write: one b128 per n-row (8 consecutive k packed).
__device__ __forceinline__ void stage_wr(const f32x4 v[8], unsigned* __restrict__ base,
                                         const int off[4]) {
#pragma unroll
    for (int i = 0; i < 4; i++) {
        uint4 q;
        q.x = pk2(v[0][i], v[1][i]);
        q.y = pk2(v[2][i], v[3][i]);
        q.z = pk2(v[4][i], v[5][i]);
        q.w = pk2(v[6][i], v[7][i]);
        *(uint4*)(base + off[i]) = q;
    }
}
// One 64-k MFMA step over the current LDS buffers.
__device__ __forceinline__ void mfma_step(const unsigned short* __restrict__ As,
                                          const unsigned short* __restrict__ Bs,
                                          f32x4 acc[4][4], int rowB, int colB, int lane) {
    int sw = (lane & 7) << 3;
#pragma unroll
    for (int kk = 0; kk < 64; kk += 32) {
        int kr = (kk + ((lane >> 4) << 3)) ^ sw;
        s16x8 af[4], bf[4];
#pragma unroll
        for (int mi = 0; mi < 4; mi++) af[mi] = *(const s16x8*)&As[(rowB + mi * 16 + (lane & 15)) * 64 + kr];
#pragma unroll
        for (int ni = 0; ni < 4; ni++) bf[ni] = *(const s16x8*)&Bs[(colB + ni * 16 + (lane & 15)) * 64 + kr];
#pragma unroll
        for (int mi = 0; mi < 4; mi++)
#pragma unroll
            for (int ni = 0; ni < 4; ni++)
                acc[mi][ni] = __builtin_amdgcn_mfma_f32_16x16x32_bf16(af[mi], bf[ni], acc[mi][ni], 0, 0, 0);
    }
}

// ---------- 1. prep: convert activations to bf16 + gate top-2 ----------
__global__ void k_prep(const float* __restrict__ hs, const float* __restrict__ gw,
                       unsigned short* __restrict__ xb,
                       int* __restrict__ topkI, float* __restrict__ topkW) {
    int cb = blockIdx.x, tid = threadIdx.x;
    int wid = tid >> 6, lane = tid & 63;
    int t = cb * 4 + wid;
    const float* xr = hs + xrow_off(t);
    unsigned short* xo = xb + (size_t)t * H_;
    float acc[E_];
#pragma unroll
    for (int e = 0; e < E_; e++) acc[e] = 0.f;
#pragma unroll
    for (int p = 0; p < 4; p++) {
        int h = p * 256 + lane * 4;
        const float4 v = *(const float4*)(xr + h);
        unsigned short o[4] = { f2bf(v.x), f2bf(v.y), f2bf(v.z), f2bf(v.w) };
        *(uint2*)(xo + h) = *(const uint2*)o;
#pragma unroll
        for (int e = 0; e < E_; e++) {
            const float4 g = *(const float4*)(gw + e * H_ + h);
            acc[e] += v.x * g.x + v.y * g.y + v.z * g.z + v.w * g.w;
        }
    }
#pragma unroll
    for (int e = 0; e < E_; e++)
        for (int off = 32; off > 0; off >>= 1) acc[e] += __shfl_down(acc[e], off);
    if (lane == 0) {
        float l0 = -1e30f, l1 = -1e30f; int i0 = 0, i1 = 0;
#pragma unroll
        for (int e = 0; e < E_; e++) {
            float v = acc[e];
            if (v > l0)      { l1 = l0; i1 = i0; l0 = v; i0 = e; }
            else if (v > l1) { l1 = v;  i1 = e; }
        }
        float p1 = expf(l1 - l0);                 // p0 = 1
        float w0 = 1.f / (1.f + p1);
        float w1s = 1.f - w0;
        topkI[2 * t] = i0; topkI[2 * t + 1] = i1;
        topkW[2 * t] = w0; topkW[2 * t + 1] = w1s;
    }
}

// ---------- 2. fused histogram + route + assign (one block) ----------
// ctrl ints: [40+e]=ntile(e)  [48+e]=slotBase(e)
__global__ void k_routeassign(const int* __restrict__ topkI, const float* __restrict__ topkW,
                              int* __restrict__ ctrl, int* __restrict__ perm,
                              int* __restrict__ slotOfTok) {
    __shared__ int s_wcnt[4][E_];
    __shared__ int s_base[E_];
    __shared__ int s_cur[E_];
    int tid = threadIdx.x, wid = tid >> 6, lane = tid & 63;
    int cnt[E_];
#pragma unroll
    for (int j = 0; j < E_; j++) cnt[j] = 0;
    for (int i = tid; i < 2 * T_; i += 256) {
        int e = topkI[i];
#pragma unroll
        for (int j = 0; j < E_; j++) cnt[j] += (e == j);
    }
#pragma unroll
    for (int j = 0; j < E_; j++)
        for (int off = 32; off > 0; off >>= 1) cnt[j] += __shfl_down(cnt[j], off);
    if (lane == 0) {
#pragma unroll
        for (int j = 0; j < E_; j++) s_wcnt[wid][j] = cnt[j];
    }
    __syncthreads();
    if (tid == 0) {
        int b = 0;
        for (int e = 0; e < E_; e++) {
            int n = s_wcnt[0][e] + s_wcnt[1][e] + s_wcnt[2][e] + s_wcnt[3][e];
            int ntile = (n + 127) >> 7;
            s_base[e] = b;
            ctrl[40 + e] = ntile;
            ctrl[48 + e] = b;
            b += ntile * 128;
        }
#pragma unroll
        for (int e = 0; e < E_; e++) s_cur[e] = 0;
    }
    __syncthreads();
    for (int s = tid; s < MAXSLOTS; s += 256) perm[s] = 0;   // padded slots -> token 0 (safe)
    __syncthreads();
    for (int t = tid; t < T_; t += 256) {
#pragma unroll
        for (int k = 0; k < 2; k++) {
            int e = topkI[2 * t + k];
            int pos = atomicAdd(&s_cur[e], 1);   // LDS atomic
            int slot = s_base[e] + pos;
            perm[slot] = t;
            slotOfTok[2 * t + k] = slot;
        }
    }
}

// ---------- 3. GEMM1 + fused swiglu epilogue ----------
// Single-buffered As/Bs (32 KB). 2-barrier K-step; bv holds B(s+1) fp32 in
// regs across the MFMA phase. launch_bounds(256,2): cap 256 VGPR -> NO SPILL
// (R7's (256,4) cap crushed to 64 VGPR and spilled bv to scratch: +27MB
// WRITE_SIZE, +13MB FETCH_SIZE, dur 83->106us).
__global__ __launch_bounds__(256, 2) void k_gemm1(
    const unsigned short* __restrict__ xb, const float* __restrict__ w1,
    const int* __restrict__ ctrl, const int* __restrict__ perm,
    unsigned short* __restrict__ A2) {
    int b  = blockIdx.x;
    int p  = ((b >> 7) << 3) | (b & 7);         // 0..175
    int ti = (b >> 3) & 15;
    int e  = p / 22;
    int ct = p - e * 22;                        // 0..21
    if (ti >= ctrl[40 + e]) return;
    int slot0 = ctrl[48 + e] + ti * 128;
    __shared__ __align__(16) unsigned short smem[2 * TSZ];   // As | Bs = 32 KB, reused as fp32 upLds
    unsigned short* As = smem;
    unsigned short* Bs = smem + TSZ;
    int tid = threadIdx.x, wid = tid >> 6, lane = tid & 63;

    // A staging map (bf16 activations, async global->LDS, pre-swizzled source)
    const unsigned short* aPtr[4];
    int lAoff[4];
#pragma unroll
    for (int i = 0; i < 4; i++) {
        int c = (wid * 4 + i) * 64 + lane;      // chunk id 0..1023
        int r = c >> 3;
        int qd = (c & 7) ^ (r & 7);             // XOR swizzle
        int tok = perm[slot0 + r];
        aPtr[i] = xb + (size_t)tok * H_ + qd * 8;
        lAoff[i] = c * 8;
    }
    // B staging map
    int h1 = tid >> 7, kp = (tid >> 4) & 7, nq = tid & 15;
    int rb = h1 * 64 + nq * 4;
    const float* bsrc = w1 + (size_t)e * (H_ * TWO_FFN)
                        + (h1 ? (FFN_ + ct * 64) : (ct * 64)) + nq * 4
                        + (size_t)(kp * 8) * TWO_FFN;
    int bwOff[4];
#pragma unroll
    for (int i = 0; i < 4; i++)
        bwOff[i] = (rb + i) * 32 + ((kp ^ ((rb + i) & 7)) << 2);

    f32x4 acc[4][4];
#pragma unroll
    for (int mi = 0; mi < 4; mi++)
#pragma unroll
        for (int ni = 0; ni < 4; ni++) acc[mi][ni] = (f32x4){0.f, 0.f, 0.f, 0.f};
    int wm = wid & 1, wn = wid >> 1;
    int rowB = wm * 64, colB = wn * 64;

    f32x4 bv[8];
    // ---- prologue ----
    load8(bv, bsrc, TWO_FFN);                                   // B(0)
    stage_wr(bv, (unsigned*)Bs, bwOff);                         // waits B(0)
#pragma unroll
    for (int i = 0; i < 4; i++) async16(aPtr[i], As + lAoff[i]); // A(0)
    load8(bv, bsrc + (size_t)64 * TWO_FFN, TWO_FFN);            // B(1) in flight
    __syncthreads();

#pragma unroll 1
    for (int s = 0; s < 16; s++) {
        mfma_step(As, Bs, acc, rowB, colB, lane);
        if (s == 15) break;
        __syncthreads();                                        // all waves done reading As/Bs
        stage_wr(bv, (unsigned*)Bs, bwOff);                     // B(s+1): bv in flight since s-1
        size_t ka = (size_t)(s + 1) * 64;
#pragma unroll
        for (int i = 0; i < 4; i++) async16(aPtr[i] + ka, As + lAoff[i]);   // A(s+1)
        if (s < 14) load8(bv, bsrc + (size_t)(s + 2) * 64 * TWO_FFN, TWO_FFN); // B(s+2)
        __syncthreads();                                        // As/Bs ready for next step
    }
    __syncthreads();
    // ---- fused swiglu epilogue ----
    float* upLds = (float*)smem;                // 128 x 64 fp32 = 32 KB
    if (wn == 1) {
#pragma unroll
        for (int mi = 0; mi < 4; mi++)
#pragma unroll
            for (int ni = 0; ni < 4; ni++)
#pragma unroll
                for (int r = 0; r < 4; r++) {
                    int m = rowB + mi * 16 + (lane >> 4) * 4 + r;
                    int u = ni * 16 + (lane & 15);
                    upLds[m * 64 + u] = acc[mi][ni][r];
                }
    }
    __syncthreads();
    if (wn == 0) {
#pragma unroll
        for (int mi = 0; mi < 4; mi++)
#pragma unroll
            for (int r = 0; r < 4; r++) {
                int m = rowB + mi * 16 + (lane >> 4) * 4 + r;
                unsigned short* arow = A2 + (size_t)(slot0 + m) * FFN_ + ct * 64;
#pragma unroll
                for (int ni = 0; ni < 4; ni++) {
                    int gl = ni * 16 + (lane & 15);
                    float g = acc[mi][ni][r];
                    float u = upLds[m * 64 + gl];
                    float s = g / (1.f + expf(-g));
                    arow[gl] = f2bf(s * u);
                }
            }
    }
}

// ---------- 4. GEMM2 (split-K=2): A2[128,1408] @ w2^T -> Yp bf16 partials ----------
__global__ __launch_bounds__(256, 2) void k_gemm2(
    const unsigned short* __restrict__ A2, const float* __restrict__ w2,
    const int* __restrict__ ctrl, unsigned short* __restrict__ Yp) {
    int b  = blockIdx.x;
    int p  = ((b >> 7) << 3) | (b & 7);         // 0..127
    int ti = (b >> 3) & 15;
    int e  = p >> 4;
    int ct = (p >> 1) & 7;                      // 0..7
    int ks = p & 1;
    if (ti >= ctrl[40 + e]) return;
    int slot0 = ctrl[48 + e] + ti * 128;
    __shared__ __align__(16) unsigned short As[TSZ];
    __shared__ __align__(16) unsigned short Bs[TSZ];
    int tid = threadIdx.x, wid = tid >> 6, lane = tid & 63;

    const unsigned short* aPtr[4];
    int lAoff[4];
#pragma unroll
    for (int i = 0; i < 4; i++) {
        int c = (wid * 4 + i) * 64 + lane;
        int r = c >> 3;
        int qd = (c & 7) ^ (r & 7);
        aPtr[i] = A2 + (size_t)(slot0 + r) * FFN_ + qd * 8;
        lAoff[i] = c * 8;
    }
    int h1 = tid >> 7, kp = (tid >> 4) & 7, nq = tid & 15;
    int rb = h1 * 64 + nq * 4;
    int kbeg = ks * (FFN_ / 2);                 // 11 steps each
    const float* bsrc = w2 + (size_t)e * (FFN_ * H_)
                        + ct * 128 + h1 * 64 + nq * 4
                        + (size_t)(kp * 8 + kbeg) * H_;
    int bwOff[4];
#pragma unroll
    for (int i = 0; i < 4; i++)
        bwOff[i] = (rb + i) * 32 + ((kp ^ ((rb + i) & 7)) << 2);

    f32x4 acc[4][4];
#pragma unroll
    for (int mi = 0; mi < 4; mi++)
#pragma unroll
        for (int ni = 0; ni < 4; ni++) acc[mi][ni] = (f32x4){0.f, 0.f, 0.f, 0.f};
    int wm = wid & 1, wn = wid >> 1;
    int rowB = wm * 64, colB = wn * 64;

    f32x4 bv[8];
    // ---- prologue ----
    load8(bv, bsrc, H_);                                        // B(0)
    stage_wr(bv, (unsigned*)Bs, bwOff);
#pragma unroll
    for (int i = 0; i < 4; i++) async16(aPtr[i] + kbeg, As + lAoff[i]);       // A(0)
    load8(bv, bsrc + (size_t)64 * H_, H_);                      // B(1)
    __syncthreads();

#pragma unroll 1
    for (int s = 0; s < 11; s++) {
        mfma_step(As, Bs, acc, rowB, colB, lane);
        if (s == 10) break;
        __syncthreads();
        stage_wr(bv, (unsigned*)Bs, bwOff);                     // B(s+1)
        size_t ka = (size_t)(s + 1) * 64;
#pragma unroll
        for (int i = 0; i < 4; i++) async16(aPtr[i] + kbeg + ka, As + lAoff[i]);  // A(s+1)
        if (s < 9) load8(bv, bsrc + (size_t)(s + 2) * 64 * H_, H_);               // B(s+2)
        __syncthreads();
    }
    unsigned short* yp = Yp + (size_t)ks * MAXSLOTS * H_;
#pragma unroll
    for (int mi = 0; mi < 4; mi++)
#pragma unroll
        for (int r = 0; r < 4; r++) {
            int m = rowB + mi * 16 + (lane >> 4) * 4 + r;
#pragma unroll
            for (int ni = 0; ni < 4; ni++) {
                int n = colB + ni * 16 + (lane & 15);
                yp[(size_t)(slot0 + m) * H_ + ct * 128 + n] = f2bf(acc[mi][ni][r]);
            }
        }
}

// ---------- 5. combine (bf16 partials) ----------
__global__ void k_combine(const unsigned short* __restrict__ Yp, const int* __restrict__ slotOfTok,
                          const float* __restrict__ topkW, float* __restrict__ out) {
    int t = blockIdx.x;
    int h = threadIdx.x * 4;
    int sA = slotOfTok[2 * t], sB = slotOfTok[2 * t + 1];
    float wA = topkW[2 * t],   wB = topkW[2 * t + 1];
    const unsigned short* pA0 = Yp + (size_t)sA * H_ + h;
    const unsigned short* pA1 = Yp + ((size_t)MAXSLOTS + sA) * H_ + h;
    const unsigned short* pB0 = Yp + (size_t)sB * H_ + h;
    const unsigned short* pB1 = Yp + ((size_t)MAXSLOTS + sB) * H_ + h;
    unsigned short a0[4], a1[4], b0[4], b1[4];
    *(uint2*)a0 = *(const uint2*)pA0;
    *(uint2*)a1 = *(const uint2*)pA1;
    *(uint2*)b0 = *(const uint2*)pB0;
    *(uint2*)b1 = *(const uint2*)pB1;
    float4 r;
    float* rp = (float*)&r;
#pragma unroll
    for (int i = 0; i < 4; i++) {
        float av = __uint_as_float(((unsigned)a0[i]) << 16) + __uint_as_float(((unsigned)a1[i]) << 16);
        float bv = __uint_as_float(((unsigned)b0[i]) << 16) + __uint_as_float(((unsigned)b1[i]) << 16);
        rp[i] = wA * av + wB * bv;
    }
    *(float4*)(out + xrow_off(t) + h) = r;
}

extern "C" void kernel_launch(void* const* d_in, const int* in_sizes, int n_in,
                              void* d_out, int out_size, void* d_ws, size_t ws_size,
                              hipStream_t stream) {
    (void)in_sizes; (void)n_in; (void)ws_size; (void)out_size;
    const float* hs = (const float*)d_in[0];
    const float* gw = (const float*)d_in[1];
    const float* w1 = (const float*)d_in[2];
    const float* w2 = (const float*)d_in[3];
    float* out = (float*)d_out;
    char* ws = (char*)d_ws;

    int*            ctrl   = (int*)ws;                                  // 1 KB
    int*            topkI  = (int*)(ws + (16u << 10));                  // 16 KB
    float*          topkW  = (float*)(ws + (48u << 10));                // 16 KB
    int*            perm   = (int*)(ws + (80u << 10));                  // 20 KB
    int*            slotOfTok = (int*)(ws + (144u << 10));              // 16 KB
    unsigned short* xb    = (unsigned short*)(ws + (1ull  << 20));      // 4 MiB
    unsigned short* A2    = (unsigned short*)(ws + (8ull  << 20));      // 13.75 MiB
    unsigned short* Yp    = (unsigned short*)(ws + (24ull << 20));      // 20 MiB -> end ~44 MiB

    k_prep<<<NB_CONV, 256, 0, stream>>>(hs, gw, xb, topkI, topkW);
    k_routeassign<<<1, 256, 0, stream>>>(topkI, topkW, ctrl, perm, slotOfTok);
    k_gemm1<<<dim3(22 * 128), 256, 0, stream>>>(xb, w1, ctrl, perm, A2);
    k_gemm2<<<dim3(16 * 128), 256, 0, stream>>>(A2, w2, ctrl, Yp);
    k_combine<<<2048, 256, 0, stream>>>(Yp, slotOfTok, topkW, out);
}